// Round 15
// baseline (442.886 us; speedup 1.0000x reference)
//
#include <hip/hip_runtime.h>
#include <cstdint>
#include <cstddef>

// Problem constants (fixed by setup_inputs)
#define ZSEQ 8
#define NSEQ 2048
#define NH 4
#define DH 128
#define QKV_STRIDE (NH * 3 * DH) /* 1536 floats per token row */
#define OUT_STRIDE (NH * DH)     /* 512 floats per token row */
#define ALPHA 0.08838834764831843f
#define LOG2E 1.4426950408889634f
#define QSCALE (ALPHA * LOG2E)                 /* fold log2e into Q */
#define VSCALE (1.0f / (2048.0f * LOG2E))      /* fold 1/(2048*log2e) into V */
#define TILE_B 16384             /* bytes per 64-row K tile / per V tile */

typedef _Float16 h8 __attribute__((ext_vector_type(8)));
typedef __fp16 fp16x2 __attribute__((ext_vector_type(2)));
typedef float fx16 __attribute__((ext_vector_type(16)));
typedef unsigned int ui4v __attribute__((ext_vector_type(4)));
typedef unsigned short u16t;

__device__ __forceinline__ h8 cvt8(float4 a, float4 b) {
  h8 r;
  r[0] = (_Float16)a.x; r[1] = (_Float16)a.y; r[2] = (_Float16)a.z; r[3] = (_Float16)a.w;
  r[4] = (_Float16)b.x; r[5] = (_Float16)b.y; r[6] = (_Float16)b.z; r[7] = (_Float16)b.w;
  return r;
}

__device__ __forceinline__ unsigned pku(float a, float b) {
  union { fp16x2 h; unsigned u; } c;
  c.h = __builtin_amdgcn_cvt_pkrtz(a, b);
  return c.u;
}

// ---------------------------------------------------------------------------
// Prep (byte-identical to verified r12): qkv f32 -> FRAGMENT-MAJOR f16 tiles.
//   Kf[zh][kt][ks=0..7][row=0..63][lh=0..1][8 f16]   (16KB per kv-tile)
//   Vf[zh][kt][ks=0..3][d=0..127][lh=0..1][8 f16]    (16KB per kv-tile)
//     V slot (ks,lh,e) holds V row n0+pi(16ks+8lh+e), pi = swap bits 2,3,
//     VSCALE pre-applied. Attn loads these coalesced directly from global.
// ---------------------------------------------------------------------------
__global__ __launch_bounds__(256) void prep_kernel(const float* __restrict__ qkv,
                                                   const int* __restrict__ seq_offsets,
                                                   char* __restrict__ kf,
                                                   char* __restrict__ vf) {
  __shared__ u16t Vl[64 * 136];  // padded transpose staging
  const int t = threadIdx.x;
  const int b = blockIdx.x;
  const int z = b >> 7;
  const int h = (b >> 5) & 3;
  const int nb = b & 31;
  const int n0 = nb * 64;
  const int start = seq_offsets[z];
  const int zh = z * NH + h;
  const size_t tb = (size_t)(zh * 32 + nb) * TILE_B;

#pragma unroll
  for (int i = 0; i < 2; ++i) {
    const int r = i * 32 + (t >> 3);
    const int ks = t & 7;
    const int c16 = ks * 16;
    const float* src = qkv + (size_t)(start + n0 + r) * QKV_STRIDE + h * (3 * DH);
    // ---- K -> fragment-major ----
    float4 a0 = *(const float4*)(src + DH + c16);
    float4 a1 = *(const float4*)(src + DH + c16 + 4);
    float4 a2 = *(const float4*)(src + DH + c16 + 8);
    float4 a3 = *(const float4*)(src + DH + c16 + 12);
    char* kd = kf + tb + ks * 2048 + r * 32;
    *(h8*)(kd) = cvt8(a0, a1);
    *(h8*)(kd + 16) = cvt8(a2, a3);
    // ---- V -> LDS (row-major, padded), pre-scaled by VSCALE ----
    float4 v0 = *(const float4*)(src + 2 * DH + c16);
    float4 v1 = *(const float4*)(src + 2 * DH + c16 + 4);
    float4 v2 = *(const float4*)(src + 2 * DH + c16 + 8);
    float4 v3 = *(const float4*)(src + 2 * DH + c16 + 12);
    v0.x *= VSCALE; v0.y *= VSCALE; v0.z *= VSCALE; v0.w *= VSCALE;
    v1.x *= VSCALE; v1.y *= VSCALE; v1.z *= VSCALE; v1.w *= VSCALE;
    v2.x *= VSCALE; v2.y *= VSCALE; v2.z *= VSCALE; v2.w *= VSCALE;
    v3.x *= VSCALE; v3.y *= VSCALE; v3.z *= VSCALE; v3.w *= VSCALE;
    *(h8*)((char*)Vl + r * 272 + c16 * 2) = cvt8(v0, v1);
    *(h8*)((char*)Vl + r * 272 + c16 * 2 + 16) = cvt8(v2, v3);
  }
  __syncthreads();
  // transpose out: fragment-major with pi (bits 2,3 of n swapped)
#pragma unroll
  for (int j = 0; j < 2; ++j) {
    const int d = j * 64 + (t >> 2);
    const int ks = t & 3;
    const int n16 = ks * 16;
    h8 o0, o1;
#pragma unroll
    for (int k2 = 0; k2 < 8; ++k2) {
      const int r0 = (k2 & 3) + 8 * (k2 >> 2);
      o0[k2] = *(const _Float16*)((const char*)Vl + (n16 + r0) * 272 + d * 2);
      o1[k2] = *(const _Float16*)((const char*)Vl + (n16 + 4 + r0) * 272 + d * 2);
    }
    char* vd = vf + tb + ks * 4096 + d * 32;
    *(h8*)(vd) = o0;        // lh=0
    *(h8*)(vd + 16) = o1;   // lh=1
  }
}

// silu + causal mask on one S^T accumulator (in place).
__device__ __forceinline__ void silu_mask(fx16& s, int nbase, bool needmask, int n0,
                                          int mrow, int lh) {
#pragma unroll
  for (int i = 0; i < 16; ++i) {
    const float sv = s[i];
    const float e2 = __builtin_amdgcn_exp2f(-sv);
    float sil = sv * __builtin_amdgcn_rcpf(1.0f + e2);
    if (needmask && (n0 + nbase + (i & 3) + 8 * (i >> 2) + 4 * lh > mrow)) sil = 0.0f;
    s[i] = sil;
  }
}

__device__ __forceinline__ h8 pack8(const fx16& s, int b) {
  union { ui4v u; h8 h; } cv;
  cv.u = (ui4v){pku(s[b + 0], s[b + 1]), pku(s[b + 2], s[b + 3]),
                pku(s[b + 4], s[b + 5]), pku(s[b + 6], s[b + 7])};
  return cv.h;
}

// ---------------------------------------------------------------------------
// Attention r16 = r12 x 4 waves/SIMD: 2048 blocks = 32 zh x 16 pairs x 4
// kv-quarters, 128 threads (2 waves), BM=64, no LDS, no barriers; K/V
// fragments loaded directly from fragment-major global (coalesced). 8
// blocks/CU = 4 waves/SIMD -> the MFMA pipe finally becomes the constraint.
// Pair p owns 64-row m-tiles {p, 31-p}: spans p+1 then 32-p = 33 tiles;
// quarter q runs j in [J[q], J[q+1]) with J = {0,9,17,25,33}. ALL flushes
// are unsafeAtomicAdd into memset-zeroed out (a tile may have 1..4 partial
// writers). Math identical to verified r4..r12.
// ---------------------------------------------------------------------------
__global__ __launch_bounds__(128, 4) void attn_kernel(const float* __restrict__ qkv,
                                                      const int* __restrict__ seq_offsets,
                                                      const char* __restrict__ kf,
                                                      const char* __restrict__ vf,
                                                      float* __restrict__ out) {
  const int t = threadIdx.x;
  const int lane = t & 63;
  const int w = t >> 6;          // 0/1
  const int l31 = lane & 31;
  const int lh = lane >> 5;

  const int bid = blockIdx.x;
  const int zh = bid & 31;       // same-zh blocks share an XCD (bid%8)
  const int p = (bid >> 5) & 15; // pair 0..15
  const int q = bid >> 9;        // quarter 0..3
  const int z = zh >> 2;
  const int h = zh & 3;
  const int start = seq_offsets[z];
  const size_t tbase = (size_t)(zh * 32) * TILE_B;
  const int spanA = p + 1;       // iters for m-tile p (1..16)
  const int jlo = (q == 0) ? 0 : (9 + 8 * (q - 1));   // {0,9,17,25}
  const int jhi = (q == 3) ? 33 : (9 + 8 * q);        // {9,17,25,33}
  const bool startsInA = (jlo < spanA);

  int mt = startsInA ? p : (31 - p);   // 64-row m-tile index
  int wm0 = mt * 64 + w * 32;
  int mrow = wm0 + l31;

  h8 qf[8];
  fx16 oacc[4];

  auto loadQ = [&]() {
    const float* qrow = qkv + (size_t)(start + mrow) * QKV_STRIDE + h * (3 * DH);
#pragma unroll
    for (int ks = 0; ks < 8; ++ks) {
      const int d0 = ks * 16 + lh * 8;
      float4 a = *(const float4*)(qrow + d0);
      float4 b = *(const float4*)(qrow + d0 + 4);
      a.x *= QSCALE; a.y *= QSCALE; a.z *= QSCALE; a.w *= QSCALE;
      b.x *= QSCALE; b.y *= QSCALE; b.z *= QSCALE; b.w *= QSCALE;
      qf[ks] = cvt8(a, b);
    }
  };
  auto zeroAcc = [&]() {
#pragma unroll
    for (int db = 0; db < 4; ++db)
#pragma unroll
      for (int i = 0; i < 16; ++i) oacc[db][i] = 0.0f;
  };
  auto flushAtomic = [&]() {
#pragma unroll
    for (int db = 0; db < 4; ++db) {
      const int d = db * 32 + l31;
#pragma unroll
      for (int i = 0; i < 16; ++i) {
        const int m = wm0 + (i & 3) + 8 * (i >> 2) + 4 * lh;
        unsafeAtomicAdd(&out[(size_t)(start + m) * OUT_STRIDE + h * DH + d], oacc[db][i]);
      }
    }
  };

  loadQ();
  zeroAcc();

  for (int j = jlo; j < jhi; ++j) {
    if (startsInA && j == spanA) {  // finished m-tile p: flush, switch
      flushAtomic();
      mt = 31 - p;
      wm0 = mt * 64 + w * 32;
      mrow = wm0 + l31;
      loadQ();
      zeroAcc();
    }
    const int kt = (j < spanA) ? j : j - spanA;
    const int n0 = kt * 64;
    const char* kb = kf + tbase + (size_t)kt * TILE_B;
    const char* vb = vf + tbase + (size_t)kt * TILE_B;

    // ---- K fragments straight from global (coalesced 2KB per instr) ----
    h8 a0[8], a1[8];
#pragma unroll
    for (int ks = 0; ks < 8; ++ks) {
      const char* kk = kb + ks * 2048 + l31 * 32 + lh * 16;
      a0[ks] = *(const h8*)(kk);
      a1[ks] = *(const h8*)(kk + 1024);
    }
    // ---- S^T = K Q^T ----
    fx16 s0, s1;
#pragma unroll
    for (int i = 0; i < 16; ++i) { s0[i] = 0.0f; s1[i] = 0.0f; }
    __builtin_amdgcn_s_setprio(1);
#pragma unroll
    for (int ks = 0; ks < 8; ++ks) {
      s0 = __builtin_amdgcn_mfma_f32_32x32x16_f16(a0[ks], qf[ks], s0, 0, 0, 0);
      s1 = __builtin_amdgcn_mfma_f32_32x32x16_f16(a1[ks], qf[ks], s1, 0, 0, 0);
    }
    __builtin_amdgcn_s_setprio(0);

    // ---- V fragments from global; silu VALU hides their latency ----
    h8 bv[4][4];
#pragma unroll
    for (int ks = 0; ks < 4; ++ks) {
#pragma unroll
      for (int db = 0; db < 4; ++db) {
        bv[ks][db] = *(const h8*)(vb + ks * 4096 + (db * 32 + l31) * 32 + lh * 16);
      }
    }
    // ---- silu + mask (in-register), pack to PV A-fragments ----
    const bool needmask = (kt == mt);
    silu_mask(s0, 0, needmask, n0, mrow, lh);
    silu_mask(s1, 32, needmask, n0, mrow, lh);
    h8 pa[4];
    pa[0] = pack8(s0, 0);
    pa[1] = pack8(s0, 8);
    pa[2] = pack8(s1, 0);
    pa[3] = pack8(s1, 8);
    // ---- O += P V ----
    __builtin_amdgcn_s_setprio(1);
#pragma unroll
    for (int ks = 0; ks < 4; ++ks) {
#pragma unroll
      for (int db = 0; db < 4; ++db) {
        oacc[db] = __builtin_amdgcn_mfma_f32_32x32x16_f16(pa[ks], bv[ks][db], oacc[db], 0, 0, 0);
      }
    }
    __builtin_amdgcn_s_setprio(0);
  }
  flushAtomic();
}

// ---------------------------------------------------------------------------
// Never-expected fallback (ws too small): naive per-(token,head) block.
// ---------------------------------------------------------------------------
__global__ __launch_bounds__(128) void fallback_kernel(const float* __restrict__ qkv,
                                                       const int* __restrict__ seq_offsets,
                                                       float* __restrict__ out) {
  const int token = blockIdx.x;
  const int h = blockIdx.y;
  const int z = token >> 11;
  const int m = token & 2047;
  const int start = seq_offsets[z];
  const int t = threadIdx.x;  // = d
  const float qd = qkv[(size_t)(start + m) * QKV_STRIDE + h * (3 * DH) + t] * ALPHA;
  __shared__ float red[2];
  float acc = 0.0f;
  for (int n = 0; n <= m; ++n) {
    const float kd = qkv[(size_t)(start + n) * QKV_STRIDE + h * (3 * DH) + DH + t];
    float part = qd * kd;
#pragma unroll
    for (int o = 32; o; o >>= 1) part += __shfl_down(part, o);
    if ((t & 63) == 0) red[t >> 6] = part;
    __syncthreads();
    const float s = red[0] + red[1];
    const float sil = s / ((1.0f + __expf(-s)) * 2048.0f);
    acc += sil * qkv[(size_t)(start + n) * QKV_STRIDE + h * (3 * DH) + 2 * DH + t];
    __syncthreads();
  }
  out[(size_t)(start + m) * OUT_STRIDE + h * DH + t] = acc;
}

// ---------------------------------------------------------------------------
extern "C" void kernel_launch(void* const* d_in, const int* in_sizes, int n_in,
                              void* d_out, int out_size, void* d_ws, size_t ws_size,
                              hipStream_t stream) {
  (void)in_sizes; (void)n_in;
  const float* qkv = (const float*)d_in[0];
  const int* seq_offsets = (const int*)d_in[1];
  // d_in[2..4] (timestamps, ts_weights, pos_weights) unused by the reference.
  float* out = (float*)d_out;

  const size_t half = (size_t)ZSEQ * NH * 32 * TILE_B;  // 16 MiB (bytes)

  if (ws_size >= 2 * half) {
    char* kf = (char*)d_ws;
    char* vf = kf + half;
    hipMemsetAsync(out, 0, (size_t)out_size * sizeof(float), stream);  // atomic targets
    prep_kernel<<<ZSEQ * NH * (NSEQ / 64), 256, 0, stream>>>(qkv, seq_offsets, kf, vf);
    attn_kernel<<<ZSEQ * NH * 16 * 4, 128, 0, stream>>>(qkv, seq_offsets, kf, vf, out);
  } else {
    fallback_kernel<<<dim3(ZSEQ * NSEQ, NH), 128, 0, stream>>>(qkv, seq_offsets, out);
  }
}

// Round 16
// 266.993 us; speedup vs baseline: 1.6588x; 1.6588x over previous
//
#include <hip/hip_runtime.h>
#include <cstdint>
#include <cstddef>

// Problem constants (fixed by setup_inputs)
#define ZSEQ 8
#define NSEQ 2048
#define NH 4
#define DH 128
#define QKV_STRIDE (NH * 3 * DH) /* 1536 floats per token row */
#define OUT_STRIDE (NH * DH)     /* 512 floats per token row */
#define ALPHA 0.08838834764831843f
#define LOG2E 1.4426950408889634f
#define QSCALE (ALPHA * LOG2E)                 /* fold log2e into Q */
#define VSCALE (1.0f / (2048.0f * LOG2E))      /* fold 1/(2048*log2e) into V */
#define TILE_B 16384             /* bytes per 64-row K tile / per V tile */

typedef _Float16 h8 __attribute__((ext_vector_type(8)));
typedef __fp16 fp16x2 __attribute__((ext_vector_type(2)));
typedef float fx16 __attribute__((ext_vector_type(16)));
typedef unsigned int ui4v __attribute__((ext_vector_type(4)));
typedef unsigned short u16t;

// global_load_lds: per-lane global src, wave-uniform LDS base (HW adds lane*16)
#define GLDS(gp, lp)                                                        \
  __builtin_amdgcn_global_load_lds(                                         \
      (__attribute__((address_space(1))) void*)(gp),                        \
      (__attribute__((address_space(3))) void*)(lp), 16, 0, 0)

__device__ __forceinline__ h8 cvt8(float4 a, float4 b) {
  h8 r;
  r[0] = (_Float16)a.x; r[1] = (_Float16)a.y; r[2] = (_Float16)a.z; r[3] = (_Float16)a.w;
  r[4] = (_Float16)b.x; r[5] = (_Float16)b.y; r[6] = (_Float16)b.z; r[7] = (_Float16)b.w;
  return r;
}

__device__ __forceinline__ unsigned pku(float a, float b) {
  union { fp16x2 h; unsigned u; } c;
  c.h = __builtin_amdgcn_cvt_pkrtz(a, b);
  return c.u;
}

// ---------------------------------------------------------------------------
// Prep (identical to verified r9/r11): qkv f32 -> pre-swizzled f16 tiles.
// ---------------------------------------------------------------------------
__global__ __launch_bounds__(256) void prep_kernel(const float* __restrict__ qkv,
                                                   const int* __restrict__ seq_offsets,
                                                   char* __restrict__ k16,
                                                   char* __restrict__ vt) {
  __shared__ u16t Vl[64 * 136];  // padded transpose staging
  const int t = threadIdx.x;
  const int b = blockIdx.x;
  const int z = b >> 7;
  const int h = (b >> 5) & 3;
  const int nb = b & 31;
  const int n0 = nb * 64;
  const int start = seq_offsets[z];
  const int zh = z * NH + h;
  const size_t tb = (size_t)(zh * 32 + nb) * TILE_B;

#pragma unroll
  for (int i = 0; i < 2; ++i) {
    const int r = i * 32 + (t >> 3);
    const int c16 = (t & 7) * 16;  // element col
    const int cb = c16 * 2;        // byte col
    const float* src = qkv + (size_t)(start + n0 + r) * QKV_STRIDE + h * (3 * DH);
    float4 a0 = *(const float4*)(src + DH + c16);
    float4 a1 = *(const float4*)(src + DH + c16 + 4);
    float4 a2 = *(const float4*)(src + DH + c16 + 8);
    float4 a3 = *(const float4*)(src + DH + c16 + 12);
    char* kd = k16 + tb + r * 256;
    *(h8*)(kd + (cb ^ ((r & 7) << 4))) = cvt8(a0, a1);
    *(h8*)(kd + ((cb + 16) ^ ((r & 7) << 4))) = cvt8(a2, a3);
    float4 v0 = *(const float4*)(src + 2 * DH + c16);
    float4 v1 = *(const float4*)(src + 2 * DH + c16 + 4);
    float4 v2 = *(const float4*)(src + 2 * DH + c16 + 8);
    float4 v3 = *(const float4*)(src + 2 * DH + c16 + 12);
    v0.x *= VSCALE; v0.y *= VSCALE; v0.z *= VSCALE; v0.w *= VSCALE;
    v1.x *= VSCALE; v1.y *= VSCALE; v1.z *= VSCALE; v1.w *= VSCALE;
    v2.x *= VSCALE; v2.y *= VSCALE; v2.z *= VSCALE; v2.w *= VSCALE;
    v3.x *= VSCALE; v3.y *= VSCALE; v3.z *= VSCALE; v3.w *= VSCALE;
    *(h8*)((char*)Vl + r * 272 + cb) = cvt8(v0, v1);
    *(h8*)((char*)Vl + r * 272 + cb + 16) = cvt8(v2, v3);
  }
  __syncthreads();
#pragma unroll
  for (int j = 0; j < 2; ++j) {
    const int d = j * 64 + (t >> 2);
    const int n16 = (t & 3) * 16;
    const int cn = n16 * 2;
    h8 o0, o1;
#pragma unroll
    for (int k2 = 0; k2 < 8; ++k2) {
      const int r0 = (k2 & 3) + 8 * (k2 >> 2);
      o0[k2] = *(const _Float16*)((const char*)Vl + (n16 + r0) * 272 + d * 2);
      o1[k2] = *(const _Float16*)((const char*)Vl + (n16 + 4 + r0) * 272 + d * 2);
    }
    char* vd = vt + tb + d * 128;
    *(h8*)(vd + (cn ^ ((d & 7) << 4))) = o0;
    *(h8*)(vd + ((cn + 16) ^ ((d & 7) << 4))) = o1;
  }
}

// silu + causal mask on one S^T accumulator (in place).
__device__ __forceinline__ void silu_mask(fx16& s, int nbase, bool needmask, int n0,
                                          int mrow, int lh) {
#pragma unroll
  for (int i = 0; i < 16; ++i) {
    const float sv = s[i];
    const float e2 = __builtin_amdgcn_exp2f(-sv);
    float sil = sv * __builtin_amdgcn_rcpf(1.0f + e2);
    if (needmask && (n0 + nbase + (i & 3) + 8 * (i >> 2) + 4 * lh > mrow)) sil = 0.0f;
    s[i] = sil;
  }
}

__device__ __forceinline__ h8 pack8(const fx16& s, int b) {
  union { ui4v u; h8 h; } cv;
  cv.u = (ui4v){pku(s[b + 0], s[b + 1]), pku(s[b + 2], s[b + 3]),
                pku(s[b + 4], s[b + 5]), pku(s[b + 6], s[b + 7])};
  return cv.h;
}

// ---------------------------------------------------------------------------
// REAL kernel: r9 verbatim (best known: 92.65us total). 512 blocks = 32 zh x
// 16 folds, 128 thr (2 waves), BM=64, dbuf LDS, fold {s, 31-s} = 33 iters.
// ---------------------------------------------------------------------------
__global__ __launch_bounds__(128, 2) void attn_kernel(const float* __restrict__ qkv,
                                                      const int* __restrict__ seq_offsets,
                                                      const char* __restrict__ k16,
                                                      const char* __restrict__ vt,
                                                      float* __restrict__ out) {
  __shared__ u16t Ks[2][64 * 128];
  __shared__ u16t Vs[2][128 * 64];

  const int t = threadIdx.x;
  const int lane = t & 63;
  const int w = t >> 6;
  const int l31 = lane & 31;
  const int lh = lane >> 5;

  const int bid = blockIdx.x;
  const int s = bid >> 5;
  const int zh = bid & 31;
  const int z = zh >> 2;
  const int h = zh & 3;
  const int start = seq_offsets[z];
  const size_t tbase = (size_t)(zh * 32) * TILE_B;
  const int spanA = s + 1;

  int mt = s;
  int wm0 = mt * 64 + w * 32;
  int mrow = wm0 + l31;

  h8 qf[8];
  fx16 oacc[4];

  auto loadQ = [&]() {
    const float* qrow = qkv + (size_t)(start + mrow) * QKV_STRIDE + h * (3 * DH);
#pragma unroll
    for (int ks = 0; ks < 8; ++ks) {
      const int d0 = ks * 16 + lh * 8;
      float4 a = *(const float4*)(qrow + d0);
      float4 b = *(const float4*)(qrow + d0 + 4);
      a.x *= QSCALE; a.y *= QSCALE; a.z *= QSCALE; a.w *= QSCALE;
      b.x *= QSCALE; b.y *= QSCALE; b.z *= QSCALE; b.w *= QSCALE;
      qf[ks] = cvt8(a, b);
    }
  };
  auto zeroAcc = [&]() {
#pragma unroll
    for (int db = 0; db < 4; ++db)
#pragma unroll
      for (int i = 0; i < 16; ++i) oacc[db][i] = 0.0f;
  };
  auto flushAcc = [&]() {
#pragma unroll
    for (int db = 0; db < 4; ++db) {
      const int d = db * 32 + l31;
#pragma unroll
      for (int i = 0; i < 16; ++i) {
        const int m = wm0 + (i & 3) + 8 * (i >> 2) + 4 * lh;
        out[(size_t)(start + m) * OUT_STRIDE + h * DH + d] = oacc[db][i];
      }
    }
  };
  auto stage = [&](int buf, int kt2) {
    const char* kg = k16 + tbase + (size_t)kt2 * TILE_B + w * 8192 + lane * 16;
    const char* vg = vt + tbase + (size_t)kt2 * TILE_B + w * 8192 + lane * 16;
    u16t* kl = &Ks[buf][w * 4096];
    u16t* vl = &Vs[buf][w * 4096];
#pragma unroll
    for (int i = 0; i < 8; ++i) {
      GLDS(kg + i * 1024, kl + i * 512);
      GLDS(vg + i * 1024, vl + i * 512);
    }
  };

  loadQ();
  zeroAcc();
  int buf = 0;
  stage(0, 0);
  __syncthreads();

  for (int j = 0; j < 33; ++j) {
    if (j == spanA) {
      flushAcc();
      mt = 31 - s;
      wm0 = mt * 64 + w * 32;
      mrow = wm0 + l31;
      loadQ();
      zeroAcc();
    }
    const int kt = (j < spanA) ? j : j - spanA;
    if (j + 1 < 33) stage(buf ^ 1, (j + 1 == spanA) ? 0 : kt + 1);

    const int n0 = kt * 64;
    {
      const char* kb = (const char*)&Ks[buf][0];
      const char* vb = (const char*)&Vs[buf][0];
      h8 a0[8], a1[8];
      const int sw = (l31 & 7) << 4;
#pragma unroll
      for (int ks = 0; ks < 8; ++ks) {
        const int cb = 32 * ks + 16 * lh;
        a0[ks] = *(const h8*)(kb + l31 * 256 + (cb ^ sw));
        a1[ks] = *(const h8*)(kb + (32 + l31) * 256 + (cb ^ sw));
      }
      fx16 s0, s1;
#pragma unroll
      for (int i = 0; i < 16; ++i) { s0[i] = 0.0f; s1[i] = 0.0f; }
      __builtin_amdgcn_s_setprio(1);
#pragma unroll
      for (int ks = 0; ks < 8; ++ks) {
        s0 = __builtin_amdgcn_mfma_f32_32x32x16_f16(a0[ks], qf[ks], s0, 0, 0, 0);
        s1 = __builtin_amdgcn_mfma_f32_32x32x16_f16(a1[ks], qf[ks], s1, 0, 0, 0);
      }
      __builtin_amdgcn_s_setprio(0);

      h8 bv[4][4];
#pragma unroll
      for (int ks = 0; ks < 4; ++ks) {
        const int cb = 32 * ks + 16 * lh;
#pragma unroll
        for (int db = 0; db < 4; ++db) {
          const int rr = db * 32 + l31;
          bv[ks][db] = *(const h8*)(vb + rr * 128 + (cb ^ ((rr & 7) << 4)));
        }
      }
      const bool needmask = (n0 + 63 > wm0);
      silu_mask(s0, 0, needmask, n0, mrow, lh);
      silu_mask(s1, 32, needmask, n0, mrow, lh);
      h8 pa[4];
      pa[0] = pack8(s0, 0);
      pa[1] = pack8(s0, 8);
      pa[2] = pack8(s1, 0);
      pa[3] = pack8(s1, 8);
      __builtin_amdgcn_s_setprio(1);
#pragma unroll
      for (int ks = 0; ks < 4; ++ks) {
#pragma unroll
        for (int db = 0; db < 4; ++db) {
          oacc[db] = __builtin_amdgcn_mfma_f32_32x32x16_f16(pa[ks], bv[ks][db], oacc[db], 0, 0, 0);
        }
      }
      __builtin_amdgcn_s_setprio(0);
    }
    __syncthreads();
    buf ^= 1;
  }
  flushAcc();
}

// ---------------------------------------------------------------------------
// ABLATION kernels (write sink to scratch; correctness-irrelevant; run AFTER
// the real kernel). MODE bits: 1=STAGE+barriers, 2=DS-reads, 4=MFMA, 8=SILU.
// Same 2-wave/128-thr/512-block shape as the real r9 kernel; no setprio.
// ---------------------------------------------------------------------------
template <int MODE>
__global__ __launch_bounds__(128, 2) void abl_kernel(const char* __restrict__ k16,
                                                     const char* __restrict__ vt,
                                                     float* __restrict__ sinkbuf,
                                                     int iters) {
  constexpr bool DO_STAGE = (MODE & 1) != 0;
  constexpr bool DO_DS = (MODE & 2) != 0;
  constexpr bool DO_MFMA = (MODE & 4) != 0;
  constexpr bool DO_SILU = (MODE & 8) != 0;
  __shared__ u16t Ks[2][64 * 128];
  __shared__ u16t Vs[2][128 * 64];

  const int t = threadIdx.x;
  const int lane = t & 63;
  const int w = t >> 6;
  const int l31 = lane & 31;
  const int lh = lane >> 5;
  const int bid = blockIdx.x;
  const int zh = bid & 31;
  const size_t tbase = (size_t)(zh * 32) * TILE_B;
  const int wm0 = 1024 + w * 32;   // m-tile beyond all kv -> always unmasked
  const int mrow = wm0 + l31;

  h8 qf[8];
#pragma unroll
  for (int ks = 0; ks < 8; ++ks)
#pragma unroll
    for (int e = 0; e < 8; ++e) qf[ks][e] = (_Float16)(0.001f * (float)((lane + ks + e) & 31));

  fx16 oacc[4];
#pragma unroll
  for (int db = 0; db < 4; ++db)
#pragma unroll
    for (int i = 0; i < 16; ++i) oacc[db][i] = 0.0f;

  float sink = 0.0f;
  int buf = 0;

  auto stage = [&](int bsel, int kt2) {
    const char* kg = k16 + tbase + (size_t)kt2 * TILE_B + w * 8192 + lane * 16;
    const char* vg = vt + tbase + (size_t)kt2 * TILE_B + w * 8192 + lane * 16;
    u16t* kl = &Ks[bsel][w * 4096];
    u16t* vl = &Vs[bsel][w * 4096];
#pragma unroll
    for (int i = 0; i < 8; ++i) {
      GLDS(kg + i * 1024, kl + i * 512);
      GLDS(vg + i * 1024, vl + i * 512);
    }
  };

  if (DO_STAGE) {
    stage(0, 0);
    __syncthreads();
  }

  for (int j = 0; j < iters; ++j) {
    if (DO_STAGE && j + 1 < iters) stage(buf ^ 1, (j + 1) & 31);
    const int n0 = (j & 15) * 64;
    const char* kb = (const char*)&Ks[DO_STAGE ? buf : 0][0];
    const char* vb = (const char*)&Vs[DO_STAGE ? buf : 0][0];
    const int sw = (l31 & 7) << 4;

    h8 a0[8], a1[8];
    if (DO_DS) {
#pragma unroll
      for (int ks = 0; ks < 8; ++ks) {
        const int cb = 32 * ks + 16 * lh;
        a0[ks] = *(const h8*)(kb + l31 * 256 + (cb ^ sw));
        a1[ks] = *(const h8*)(kb + (32 + l31) * 256 + (cb ^ sw));
      }
    } else {
#pragma unroll
      for (int ks = 0; ks < 8; ++ks) { a0[ks] = qf[ks]; a1[ks] = qf[(ks + 1) & 7]; }
    }

    fx16 s0, s1;
    if (DO_MFMA) {
#pragma unroll
      for (int i = 0; i < 16; ++i) { s0[i] = 0.0f; s1[i] = 0.0f; }
#pragma unroll
      for (int ks = 0; ks < 8; ++ks) {
        s0 = __builtin_amdgcn_mfma_f32_32x32x16_f16(a0[ks], qf[ks], s0, 0, 0, 0);
        s1 = __builtin_amdgcn_mfma_f32_32x32x16_f16(a1[ks], qf[ks], s1, 0, 0, 0);
      }
    } else {
#pragma unroll
      for (int i = 0; i < 16; ++i) {
        s0[i] = (float)a0[i & 7][(i >> 3) & 7];
        s1[i] = (float)a1[i & 7][(i >> 3) & 7];
      }
    }

    h8 bv[4][4];
    if (DO_DS) {
#pragma unroll
      for (int ks = 0; ks < 4; ++ks) {
        const int cb = 32 * ks + 16 * lh;
#pragma unroll
        for (int db = 0; db < 4; ++db) {
          const int rr = db * 32 + l31;
          bv[ks][db] = *(const h8*)(vb + rr * 128 + (cb ^ ((rr & 7) << 4)));
        }
      }
    } else {
#pragma unroll
      for (int ks = 0; ks < 4; ++ks)
#pragma unroll
        for (int db = 0; db < 4; ++db) bv[ks][db] = qf[(ks + db) & 7];
    }

    const bool needmask = (j == 15);
    if (DO_SILU) {
      silu_mask(s0, 0, needmask, n0, mrow, lh);
      silu_mask(s1, 32, needmask, n0, mrow, lh);
    } else {
#pragma unroll
      for (int i = 0; i < 16; ++i) { s0[i] *= 0.0009765625f; s1[i] *= 0.0009765625f; }
    }
    h8 pa[4];
    pa[0] = pack8(s0, 0);
    pa[1] = pack8(s0, 8);
    pa[2] = pack8(s1, 0);
    pa[3] = pack8(s1, 8);

    if (DO_MFMA) {
#pragma unroll
      for (int ks = 0; ks < 4; ++ks) {
#pragma unroll
        for (int db = 0; db < 4; ++db) {
          oacc[db] = __builtin_amdgcn_mfma_f32_32x32x16_f16(pa[ks], bv[ks][db], oacc[db], 0, 0, 0);
        }
      }
    } else {
#pragma unroll
      for (int ks = 0; ks < 4; ++ks)
        sink += (float)pa[ks][0] + (float)bv[ks][0][0] + (float)bv[ks][3][7];
    }

    if (DO_STAGE) {
      __syncthreads();
      buf ^= 1;
    }
  }
#pragma unroll
  for (int db = 0; db < 4; ++db)
#pragma unroll
    for (int i = 0; i < 16; ++i) sink += oacc[db][i];
  sinkbuf[bid * 128 + t] = sink;  // keep-alive store (scratch)
}

// ---------------------------------------------------------------------------
// Never-expected fallback (ws too small): naive per-(token,head) block.
// ---------------------------------------------------------------------------
__global__ __launch_bounds__(128) void fallback_kernel(const float* __restrict__ qkv,
                                                       const int* __restrict__ seq_offsets,
                                                       float* __restrict__ out) {
  const int token = blockIdx.x;
  const int h = blockIdx.y;
  const int z = token >> 11;
  const int m = token & 2047;
  const int start = seq_offsets[z];
  const int t = threadIdx.x;  // = d
  const float qd = qkv[(size_t)(start + m) * QKV_STRIDE + h * (3 * DH) + t] * ALPHA;
  __shared__ float red[2];
  float acc = 0.0f;
  for (int n = 0; n <= m; ++n) {
    const float kd = qkv[(size_t)(start + n) * QKV_STRIDE + h * (3 * DH) + DH + t];
    float part = qd * kd;
#pragma unroll
    for (int o = 32; o; o >>= 1) part += __shfl_down(part, o);
    if ((t & 63) == 0) red[t >> 6] = part;
    __syncthreads();
    const float s = red[0] + red[1];
    const float sil = s / ((1.0f + __expf(-s)) * 2048.0f);
    acc += sil * qkv[(size_t)(start + n) * QKV_STRIDE + h * (3 * DH) + 2 * DH + t];
    __syncthreads();
  }
  out[(size_t)(start + m) * OUT_STRIDE + h * DH + t] = acc;
}

// ---------------------------------------------------------------------------
extern "C" void kernel_launch(void* const* d_in, const int* in_sizes, int n_in,
                              void* d_out, int out_size, void* d_ws, size_t ws_size,
                              hipStream_t stream) {
  (void)in_sizes; (void)n_in; (void)out_size;
  const float* qkv = (const float*)d_in[0];
  const int* seq_offsets = (const int*)d_in[1];
  float* out = (float*)d_out;

  const size_t half = (size_t)ZSEQ * NH * 32 * TILE_B;  // 16 MiB (bytes)

  if (ws_size >= 2 * half) {
    char* k16 = (char*)d_ws;
    char* vt = k16 + half;
    prep_kernel<<<ZSEQ * NH * (NSEQ / 64), 256, 0, stream>>>(qkv, seq_offsets, k16, vt);
    attn_kernel<<<ZSEQ * NH * 16, 128, 0, stream>>>(qkv, seq_offsets, k16, vt, out);
    // ---- ablation dispatches (write to scratch AFTER real kernel done) ----
    float* sink = (float*)d_ws;  // clobbers k16 region; values irrelevant now
    abl_kernel<15><<<512, 128, 0, stream>>>(k16, vt, sink, 16);  // full
    abl_kernel<7><<<512, 128, 0, stream>>>(k16, vt, sink, 16);   // no silu
    abl_kernel<11><<<512, 128, 0, stream>>>(k16, vt, sink, 16);  // no MFMA
    abl_kernel<14><<<512, 128, 0, stream>>>(k16, vt, sink, 16);  // no stage/barrier
    abl_kernel<12><<<512, 128, 0, stream>>>(k16, vt, sink, 64);  // reg-only compute
  } else {
    fallback_kernel<<<dim3(ZSEQ * NSEQ, NH), 128, 0, stream>>>(qkv, seq_offsets, out);
  }
}

// Round 17
// 99.338 us; speedup vs baseline: 4.4584x; 2.6877x over previous
//
#include <hip/hip_runtime.h>
#include <cstdint>
#include <cstddef>

// Problem constants (fixed by setup_inputs)
#define ZSEQ 8
#define NSEQ 2048
#define NH 4
#define DH 128
#define QKV_STRIDE (NH * 3 * DH) /* 1536 floats per token row */
#define OUT_STRIDE (NH * DH)     /* 512 floats per token row */
#define ALPHA 0.08838834764831843f
#define LOG2E 1.4426950408889634f
#define QSCALE (ALPHA * LOG2E)                 /* fold log2e into Q */
#define VSCALE (1.0f / (2048.0f * LOG2E))      /* fold 1/(2048*log2e) into V */
#define TILE_B 16384             /* bytes per 64-row K tile / per V tile */

typedef _Float16 h8 __attribute__((ext_vector_type(8)));
typedef __fp16 fp16x2 __attribute__((ext_vector_type(2)));
typedef float fx16 __attribute__((ext_vector_type(16)));
typedef unsigned int ui4v __attribute__((ext_vector_type(4)));
typedef unsigned short u16t;

// global_load_lds: per-lane global src, wave-uniform LDS base (HW adds lane*16)
#define GLDS(gp, lp)                                                        \
  __builtin_amdgcn_global_load_lds(                                         \
      (__attribute__((address_space(1))) void*)(gp),                        \
      (__attribute__((address_space(3))) void*)(lp), 16, 0, 0)

__device__ __forceinline__ h8 cvt8(float4 a, float4 b) {
  h8 r;
  r[0] = (_Float16)a.x; r[1] = (_Float16)a.y; r[2] = (_Float16)a.z; r[3] = (_Float16)a.w;
  r[4] = (_Float16)b.x; r[5] = (_Float16)b.y; r[6] = (_Float16)b.z; r[7] = (_Float16)b.w;
  return r;
}

__device__ __forceinline__ unsigned pku(float a, float b) {
  union { fp16x2 h; unsigned u; } c;
  c.h = __builtin_amdgcn_cvt_pkrtz(a, b);
  return c.u;
}

// ---------------------------------------------------------------------------
// Prep (identical to verified r9/r11): qkv f32 -> pre-swizzled f16 tiles.
//   K tiles: [zh][nt][64 rows x 256B], byte col c stored at c ^ ((row&7)<<4)
//   V tiles: [zh][nt][128 d-rows x 128B], col c stored at c ^ ((d&7)<<4)
//   V pre-scaled by VSCALE; V column order pi = swap bits 2,3 of n.
// ---------------------------------------------------------------------------
__global__ __launch_bounds__(256) void prep_kernel(const float* __restrict__ qkv,
                                                   const int* __restrict__ seq_offsets,
                                                   char* __restrict__ k16,
                                                   char* __restrict__ vt) {
  __shared__ u16t Vl[64 * 136];  // padded transpose staging
  const int t = threadIdx.x;
  const int b = blockIdx.x;
  const int z = b >> 7;
  const int h = (b >> 5) & 3;
  const int nb = b & 31;
  const int n0 = nb * 64;
  const int start = seq_offsets[z];
  const int zh = z * NH + h;
  const size_t tb = (size_t)(zh * 32 + nb) * TILE_B;

#pragma unroll
  for (int i = 0; i < 2; ++i) {
    const int r = i * 32 + (t >> 3);
    const int c16 = (t & 7) * 16;  // element col
    const int cb = c16 * 2;        // byte col
    const float* src = qkv + (size_t)(start + n0 + r) * QKV_STRIDE + h * (3 * DH);
    float4 a0 = *(const float4*)(src + DH + c16);
    float4 a1 = *(const float4*)(src + DH + c16 + 4);
    float4 a2 = *(const float4*)(src + DH + c16 + 8);
    float4 a3 = *(const float4*)(src + DH + c16 + 12);
    char* kd = k16 + tb + r * 256;
    *(h8*)(kd + (cb ^ ((r & 7) << 4))) = cvt8(a0, a1);
    *(h8*)(kd + ((cb + 16) ^ ((r & 7) << 4))) = cvt8(a2, a3);
    float4 v0 = *(const float4*)(src + 2 * DH + c16);
    float4 v1 = *(const float4*)(src + 2 * DH + c16 + 4);
    float4 v2 = *(const float4*)(src + 2 * DH + c16 + 8);
    float4 v3 = *(const float4*)(src + 2 * DH + c16 + 12);
    v0.x *= VSCALE; v0.y *= VSCALE; v0.z *= VSCALE; v0.w *= VSCALE;
    v1.x *= VSCALE; v1.y *= VSCALE; v1.z *= VSCALE; v1.w *= VSCALE;
    v2.x *= VSCALE; v2.y *= VSCALE; v2.z *= VSCALE; v2.w *= VSCALE;
    v3.x *= VSCALE; v3.y *= VSCALE; v3.z *= VSCALE; v3.w *= VSCALE;
    *(h8*)((char*)Vl + r * 272 + cb) = cvt8(v0, v1);
    *(h8*)((char*)Vl + r * 272 + cb + 16) = cvt8(v2, v3);
  }
  __syncthreads();
#pragma unroll
  for (int j = 0; j < 2; ++j) {
    const int d = j * 64 + (t >> 2);
    const int n16 = (t & 3) * 16;
    const int cn = n16 * 2;
    h8 o0, o1;
#pragma unroll
    for (int k2 = 0; k2 < 8; ++k2) {
      const int r0 = (k2 & 3) + 8 * (k2 >> 2);
      o0[k2] = *(const _Float16*)((const char*)Vl + (n16 + r0) * 272 + d * 2);
      o1[k2] = *(const _Float16*)((const char*)Vl + (n16 + 4 + r0) * 272 + d * 2);
    }
    char* vd = vt + tb + d * 128;
    *(h8*)(vd + (cn ^ ((d & 7) << 4))) = o0;
    *(h8*)(vd + ((cn + 16) ^ ((d & 7) << 4))) = o1;
  }
}

// silu + causal mask on one S^T accumulator (in place).
// s element i at n = n0 + nbase + (i&3) + 8*(i>>2) + 4*lh, col m = mrow.
__device__ __forceinline__ void silu_mask(fx16& s, int nbase, bool needmask, int n0,
                                          int mrow, int lh) {
#pragma unroll
  for (int i = 0; i < 16; ++i) {
    const float sv = s[i];
    const float e2 = __builtin_amdgcn_exp2f(-sv);
    float sil = sv * __builtin_amdgcn_rcpf(1.0f + e2);
    if (needmask && (n0 + nbase + (i & 3) + 8 * (i >> 2) + 4 * lh > mrow)) sil = 0.0f;
    s[i] = sil;
  }
}

__device__ __forceinline__ h8 pack8(const fx16& s, int b) {
  union { ui4v u; h8 h; } cv;
  cv.u = (ui4v){pku(s[b + 0], s[b + 1]), pku(s[b + 2], s[b + 3]),
                pku(s[b + 4], s[b + 5]), pku(s[b + 6], s[b + 7])};
  return cv.h;
}

// ---------------------------------------------------------------------------
// Attention r17 = r9 + compute-chain surgery (r16 ablation: pure-register
// compute = 3316 cyc/iter = 58% of wall; MFMA dep-latency-bound, pipe 28%).
//   1. QK split-K: FOUR interleaved MFMA chains of depth 4 (was 2 x depth 8)
//      + f32 merges -> QK critical path halved.
//   2. PV reordered: merge/silu/pack(s0) -> PV ks0/1; merge/silu(s1) VALU
//      overlaps PV-A MFMAs -> PV ks2/3.
//   3. setprio removed.
// Everything else (512 blocks = 32 zh x 16 folds, 2 waves, BM=64, dbuf LDS,
// GLDS staging, fold {s,31-s} = 33 uniform iters, layouts) verbatim r9.
// ---------------------------------------------------------------------------
__global__ __launch_bounds__(128, 2) void attn_kernel(const float* __restrict__ qkv,
                                                      const int* __restrict__ seq_offsets,
                                                      const char* __restrict__ k16,
                                                      const char* __restrict__ vt,
                                                      float* __restrict__ out) {
  __shared__ u16t Ks[2][64 * 128];
  __shared__ u16t Vs[2][128 * 64];

  const int t = threadIdx.x;
  const int lane = t & 63;
  const int w = t >> 6;
  const int l31 = lane & 31;
  const int lh = lane >> 5;

  const int bid = blockIdx.x;
  const int s = bid >> 5;
  const int zh = bid & 31;
  const int z = zh >> 2;
  const int h = zh & 3;
  const int start = seq_offsets[z];
  const size_t tbase = (size_t)(zh * 32) * TILE_B;
  const int spanA = s + 1;

  int mt = s;
  int wm0 = mt * 64 + w * 32;
  int mrow = wm0 + l31;

  h8 qf[8];
  fx16 oacc[4];

  auto loadQ = [&]() {
    const float* qrow = qkv + (size_t)(start + mrow) * QKV_STRIDE + h * (3 * DH);
#pragma unroll
    for (int ks = 0; ks < 8; ++ks) {
      const int d0 = ks * 16 + lh * 8;
      float4 a = *(const float4*)(qrow + d0);
      float4 b = *(const float4*)(qrow + d0 + 4);
      a.x *= QSCALE; a.y *= QSCALE; a.z *= QSCALE; a.w *= QSCALE;
      b.x *= QSCALE; b.y *= QSCALE; b.z *= QSCALE; b.w *= QSCALE;
      qf[ks] = cvt8(a, b);
    }
  };
  auto zeroAcc = [&]() {
#pragma unroll
    for (int db = 0; db < 4; ++db)
#pragma unroll
      for (int i = 0; i < 16; ++i) oacc[db][i] = 0.0f;
  };
  auto flushAcc = [&]() {
#pragma unroll
    for (int db = 0; db < 4; ++db) {
      const int d = db * 32 + l31;
#pragma unroll
      for (int i = 0; i < 16; ++i) {
        const int m = wm0 + (i & 3) + 8 * (i >> 2) + 4 * lh;
        out[(size_t)(start + m) * OUT_STRIDE + h * DH + d] = oacc[db][i];
      }
    }
  };
  auto stage = [&](int buf, int kt2) {
    const char* kg = k16 + tbase + (size_t)kt2 * TILE_B + w * 8192 + lane * 16;
    const char* vg = vt + tbase + (size_t)kt2 * TILE_B + w * 8192 + lane * 16;
    u16t* kl = &Ks[buf][w * 4096];
    u16t* vl = &Vs[buf][w * 4096];
#pragma unroll
    for (int i = 0; i < 8; ++i) {
      GLDS(kg + i * 1024, kl + i * 512);
      GLDS(vg + i * 1024, vl + i * 512);
    }
  };

  loadQ();
  zeroAcc();
  int buf = 0;
  stage(0, 0);
  __syncthreads();

  for (int j = 0; j < 33; ++j) {
    if (j == spanA) {
      flushAcc();
      mt = 31 - s;
      wm0 = mt * 64 + w * 32;
      mrow = wm0 + l31;
      loadQ();
      zeroAcc();
    }
    const int kt = (j < spanA) ? j : j - spanA;
    if (j + 1 < 33) stage(buf ^ 1, (j + 1 == spanA) ? 0 : kt + 1);

    const int n0 = kt * 64;
    {
      const char* kb = (const char*)&Ks[buf][0];
      const char* vb = (const char*)&Vs[buf][0];
      h8 a0[8], a1[8];
      const int sw = (l31 & 7) << 4;
#pragma unroll
      for (int ks = 0; ks < 8; ++ks) {
        const int cb = 32 * ks + 16 * lh;
        a0[ks] = *(const h8*)(kb + l31 * 256 + (cb ^ sw));
        a1[ks] = *(const h8*)(kb + (32 + l31) * 256 + (cb ^ sw));
      }
      // ---- S^T = K Q^T : FOUR interleaved chains of depth 4 ----
      fx16 s0a, s0b, s1a, s1b;
#pragma unroll
      for (int i = 0; i < 16; ++i) { s0a[i] = 0.0f; s0b[i] = 0.0f; s1a[i] = 0.0f; s1b[i] = 0.0f; }
#pragma unroll
      for (int ks = 0; ks < 4; ++ks) {
        s0a = __builtin_amdgcn_mfma_f32_32x32x16_f16(a0[ks], qf[ks], s0a, 0, 0, 0);
        s1a = __builtin_amdgcn_mfma_f32_32x32x16_f16(a1[ks], qf[ks], s1a, 0, 0, 0);
        s0b = __builtin_amdgcn_mfma_f32_32x32x16_f16(a0[ks + 4], qf[ks + 4], s0b, 0, 0, 0);
        s1b = __builtin_amdgcn_mfma_f32_32x32x16_f16(a1[ks + 4], qf[ks + 4], s1b, 0, 0, 0);
      }

      // ---- V fragments (independent of QK; latency hidden by MFMAs) ----
      h8 bv[4][4];
#pragma unroll
      for (int ks = 0; ks < 4; ++ks) {
        const int cb = 32 * ks + 16 * lh;
#pragma unroll
        for (int db = 0; db < 4; ++db) {
          const int rr = db * 32 + l31;
          bv[ks][db] = *(const h8*)(vb + rr * 128 + (cb ^ ((rr & 7) << 4)));
        }
      }

      const bool needmask = (n0 + 63 > wm0);
      // ---- group A: merge s0, silu, pack, PV ks0/1 ----
      fx16 s0 = s0a + s0b;
      silu_mask(s0, 0, needmask, n0, mrow, lh);
      h8 pa0 = pack8(s0, 0);
      h8 pa1 = pack8(s0, 8);
#pragma unroll
      for (int db = 0; db < 4; ++db)
        oacc[db] = __builtin_amdgcn_mfma_f32_32x32x16_f16(pa0, bv[0][db], oacc[db], 0, 0, 0);
      // group B merge/silu on VALU overlaps group A PV MFMAs
      fx16 s1 = s1a + s1b;
      silu_mask(s1, 32, needmask, n0, mrow, lh);
#pragma unroll
      for (int db = 0; db < 4; ++db)
        oacc[db] = __builtin_amdgcn_mfma_f32_32x32x16_f16(pa1, bv[1][db], oacc[db], 0, 0, 0);
      h8 pa2 = pack8(s1, 0);
      h8 pa3 = pack8(s1, 8);
#pragma unroll
      for (int db = 0; db < 4; ++db)
        oacc[db] = __builtin_amdgcn_mfma_f32_32x32x16_f16(pa2, bv[2][db], oacc[db], 0, 0, 0);
#pragma unroll
      for (int db = 0; db < 4; ++db)
        oacc[db] = __builtin_amdgcn_mfma_f32_32x32x16_f16(pa3, bv[3][db], oacc[db], 0, 0, 0);
    }
    __syncthreads();
    buf ^= 1;
  }
  flushAcc();
}

// ---------------------------------------------------------------------------
// Never-expected fallback (ws too small): naive per-(token,head) block.
// ---------------------------------------------------------------------------
__global__ __launch_bounds__(128) void fallback_kernel(const float* __restrict__ qkv,
                                                       const int* __restrict__ seq_offsets,
                                                       float* __restrict__ out) {
  const int token = blockIdx.x;
  const int h = blockIdx.y;
  const int z = token >> 11;
  const int m = token & 2047;
  const int start = seq_offsets[z];
  const int t = threadIdx.x;  // = d
  const float qd = qkv[(size_t)(start + m) * QKV_STRIDE + h * (3 * DH) + t] * ALPHA;
  __shared__ float red[2];
  float acc = 0.0f;
  for (int n = 0; n <= m; ++n) {
    const float kd = qkv[(size_t)(start + n) * QKV_STRIDE + h * (3 * DH) + DH + t];
    float part = qd * kd;
#pragma unroll
    for (int o = 32; o; o >>= 1) part += __shfl_down(part, o);
    if ((t & 63) == 0) red[t >> 6] = part;
    __syncthreads();
    const float s = red[0] + red[1];
    const float sil = s / ((1.0f + __expf(-s)) * 2048.0f);
    acc += sil * qkv[(size_t)(start + n) * QKV_STRIDE + h * (3 * DH) + 2 * DH + t];
    __syncthreads();
  }
  out[(size_t)(start + m) * OUT_STRIDE + h * DH + t] = acc;
}

// ---------------------------------------------------------------------------
extern "C" void kernel_launch(void* const* d_in, const int* in_sizes, int n_in,
                              void* d_out, int out_size, void* d_ws, size_t ws_size,
                              hipStream_t stream) {
  (void)in_sizes; (void)n_in; (void)out_size;
  const float* qkv = (const float*)d_in[0];
  const int* seq_offsets = (const int*)d_in[1];
  // d_in[2..4] (timestamps, ts_weights, pos_weights) unused by the reference.
  float* out = (float*)d_out;

  const size_t half = (size_t)ZSEQ * NH * 32 * TILE_B;  // 16 MiB (bytes)

  if (ws_size >= 2 * half) {
    char* k16 = (char*)d_ws;
    char* vt = k16 + half;
    prep_kernel<<<ZSEQ * NH * (NSEQ / 64), 256, 0, stream>>>(qkv, seq_offsets, k16, vt);
    attn_kernel<<<ZSEQ * NH * 16, 128, 0, stream>>>(qkv, seq_offsets, k16, vt, out);
  } else {
    fallback_kernel<<<dim3(ZSEQ * NSEQ, NH), 128, 0, stream>>>(qkv, seq_offsets, out);
  }
}